// Round 7
// baseline (443.539 us; speedup 1.0000x reference)
//
#include <hip/hip_runtime.h>
#include <hip/hip_bf16.h>

#define N_NODES 50000
#define N_EDGES 800000
#define ET_EDGES 850000   // + self loops
#define HEADS 4
#define NBLK 49           // ceil(N_NODES/1024)

__device__ __forceinline__ float lrelu(float v) { return v > 0.f ? v : 0.2f * v; }

__device__ __forceinline__ void edge_sd(const int* __restrict__ ei, int e, int& s, int& d) {
    if (e < N_EDGES) { s = ei[e]; d = ei[N_EDGES + e]; }
    else { s = d = e - N_EDGES; }
}

// ---------------- CSR build ----------------
__global__ __launch_bounds__(256) void count_kernel(const int* __restrict__ ei, int* __restrict__ deg) {
    int e = blockIdx.x * 256 + threadIdx.x;
    if (e >= ET_EDGES) return;
    int s, d; edge_sd(ei, e, s, d);
    atomicAdd(deg + d, 1);
}

__global__ __launch_bounds__(1024) void scanA_kernel(const int* __restrict__ deg,
                                                     int* __restrict__ rowp, int* __restrict__ bsum) {
    __shared__ int s_wt[16];
    __shared__ int s_we[16];
    int tid = threadIdx.x;
    int wid = tid >> 6, lane = tid & 63;
    int i = blockIdx.x * 1024 + tid;
    int v = (i < N_NODES) ? deg[i] : 0;
    int x = v;
    #pragma unroll
    for (int off = 1; off < 64; off <<= 1) {
        int t = __shfl_up(x, off);
        if (lane >= off) x += t;
    }
    if (lane == 63) s_wt[wid] = x;
    __syncthreads();
    if (tid < 16) {
        int wv = s_wt[tid];
        int y = wv;
        #pragma unroll
        for (int off = 1; off < 16; off <<= 1) {
            int t = __shfl_up(y, off);
            if (tid >= off) y += t;
        }
        s_we[tid] = y - wv;
    }
    __syncthreads();
    int excl = x - v + s_we[wid];
    if (i < N_NODES) rowp[i] = excl;
    if (tid == 1023) bsum[blockIdx.x] = excl + v;
}

__global__ __launch_bounds__(64) void scanB_kernel(const int* __restrict__ bsum,
                                                   int* __restrict__ boff, int* __restrict__ rowp) {
    int lane = threadIdx.x;
    int v = (lane < NBLK) ? bsum[lane] : 0;
    int x = v;
    #pragma unroll
    for (int off = 1; off < 64; off <<= 1) {
        int t = __shfl_up(x, off);
        if (lane >= off) x += t;
    }
    if (lane < NBLK) boff[lane] = x - v;
    if (lane == NBLK - 1) rowp[N_NODES] = x;
}

__global__ __launch_bounds__(256) void scanC_kernel(int* __restrict__ rowp,
                                                    const int* __restrict__ boff, int* __restrict__ cursor) {
    int i = blockIdx.x * 256 + threadIdx.x;
    if (i >= N_NODES) return;
    int v = rowp[i] + boff[i >> 10];
    rowp[i] = v;
    cursor[i] = v;
}

__global__ __launch_bounds__(256) void scatter_kernel(const int* __restrict__ ei,
                                                      int* __restrict__ cursor, int* __restrict__ csr_src) {
    int e = blockIdx.x * 256 + threadIdx.x;
    if (e >= ET_EDGES) return;
    int s, d; edge_sd(ei, e, s, d);
    int pos = atomicAdd(cursor + d, 1);
    csr_src[pos] = s;
}

// ---------------- fold attention vectors through g1_w ----------------
__global__ __launch_bounds__(256) void fold1_kernel(
    const float* __restrict__ g1w, const float* __restrict__ g1as, const float* __restrict__ g1ad,
    float* __restrict__ wsf, float* __restrict__ wdf) {
    int tid = threadIdx.x;       // tid = h*64+k
    int h = tid >> 6, k = tid & 63;
    float as_acc = 0.f, ad_acc = 0.f;
    #pragma unroll 8
    for (int c = 0; c < 64; ++c) {
        float w = g1w[k * 256 + h * 64 + c];
        as_acc += w * g1as[h * 64 + c];
        ad_acc += w * g1ad[h * 64 + c];
    }
    wsf[tid] = as_acc;
    wdf[tid] = ad_acc;
}

// ---------------- encoder (32 nodes/block) + fused alpha1 ----------------
__global__ __launch_bounds__(256) void encoder32_kernel(
    const float* __restrict__ x, const float* __restrict__ w1, const float* __restrict__ b1,
    const float* __restrict__ w2, const float* __restrict__ b2,
    const float* __restrict__ wsf, const float* __restrict__ wdf,
    float* __restrict__ henc, float* __restrict__ as1, float* __restrict__ ad1) {
    __shared__ float s_w2[4096];     // w2[64][64]
    __shared__ float s_t[32][64];
    __shared__ float s_x[32][8];
    __shared__ float s_he[32][65];   // +1 pad
    __shared__ float s_wf[8 * 65];
    int tid = threadIdx.x;
    int node0 = blockIdx.x * 32;
    for (int i = tid; i < 4096; i += 256) s_w2[i] = w2[i];
    for (int i = tid; i < 224; i += 256) {
        int src = node0 * 7 + i;
        s_x[i / 7][i % 7] = (src < N_NODES * 7) ? x[src] : 0.f;
    }
    for (int i = tid; i < 512; i += 256) {
        int g = i >> 6, k = i & 63;
        int h = g & 3;
        s_wf[g * 65 + k] = (g < 4) ? wsf[h * 64 + k] : wdf[h * 64 + k];
    }
    int c = tid & 63;
    int mg = tid >> 6;
    float w1c[7];
    #pragma unroll
    for (int k = 0; k < 7; ++k) w1c[k] = w1[k * 64 + c];
    float b1c = b1[c];
    __syncthreads();
    #pragma unroll
    for (int m = 0; m < 8; ++m) {
        int nn = mg * 8 + m;
        float a = b1c;
        #pragma unroll
        for (int k = 0; k < 7; ++k) a += s_x[nn][k] * w1c[k];
        s_t[nn][c] = fmaxf(a, 0.f);
    }
    __syncthreads();
    float acc[8];
    float b2c = b2[c];
    #pragma unroll
    for (int m = 0; m < 8; ++m) acc[m] = b2c;
    #pragma unroll 4
    for (int k = 0; k < 64; ++k) {
        float w = s_w2[k * 64 + c];
        #pragma unroll
        for (int m = 0; m < 8; ++m) acc[m] += s_t[mg * 8 + m][k] * w;
    }
    #pragma unroll
    for (int m = 0; m < 8; ++m) {
        int nn = mg * 8 + m;
        int node = node0 + nn;
        s_he[nn][c] = acc[m];
        if (node < N_NODES) henc[node * 64 + c] = acc[m];
    }
    __syncthreads();
    {
        int nn = tid >> 3, r = tid & 7;
        int node = node0 + nn;
        const float* wf = s_wf + r * 65;
        float sum = 0.f;
        #pragma unroll 8
        for (int k = 0; k < 64; ++k) sum += s_he[nn][k] * wf[k];
        if (node < N_NODES) {
            int hh = r & 3;
            if (r < 4) as1[node * 4 + hh] = sum;
            else       ad1[node * 4 + hh] = sum;
        }
    }
}

// ---------------- GAT1 aggregation, single-pass softmax ----------------
__global__ __launch_bounds__(256) void aggregate1_kernel(
    const int* __restrict__ row, const int* __restrict__ csr_src,
    const float* __restrict__ as, const float* __restrict__ ad,
    const float* __restrict__ henc, float* __restrict__ agg) {
    int wslot = threadIdx.x >> 6;
    int lane  = threadIdx.x & 63;
    int n = blockIdx.x * 4 + wslot;
    __shared__ int    ls[4][64];
    __shared__ float4 lp4[4][64];
    if (n >= N_NODES) return;
    int base = row[n];
    int deg  = row[n + 1] - base;
    float4 add = *(const float4*)(ad + n * 4);

    float4 l = make_float4(0.f, 0.f, 0.f, 0.f);
    float4 acc = make_float4(0.f, 0.f, 0.f, 0.f);
    for (int c0 = 0; c0 < deg; c0 += 64) {
        int j = c0 + lane;
        int s = 0;
        float4 p = make_float4(0.f, 0.f, 0.f, 0.f);
        if (j < deg) {
            s = csr_src[base + j];
            float4 a = *(const float4*)(as + s * 4);
            p.x = __expf(lrelu(a.x + add.x));
            p.y = __expf(lrelu(a.y + add.y));
            p.z = __expf(lrelu(a.z + add.z));
            p.w = __expf(lrelu(a.w + add.w));
        }
        ls[wslot][lane] = s;
        lp4[wslot][lane] = p;
        float4 t = p;
        #pragma unroll
        for (int off = 32; off > 0; off >>= 1) {
            t.x += __shfl_xor(t.x, off);
            t.y += __shfl_xor(t.y, off);
            t.z += __shfl_xor(t.z, off);
            t.w += __shfl_xor(t.w, off);
        }
        l.x += t.x; l.y += t.y; l.z += t.z; l.w += t.w;
        int cnt = min(64, deg - c0);
        const int*    lsw = ls[wslot];
        const float4* lpw = lp4[wslot];
        int j2 = 0;
        for (; j2 + 4 <= cnt; j2 += 4) {
            int a0 = lsw[j2+0] * 64 + lane;
            int a1 = lsw[j2+1] * 64 + lane;
            int a2 = lsw[j2+2] * 64 + lane;
            int a3 = lsw[j2+3] * 64 + lane;
            float v0 = henc[a0], v1 = henc[a1], v2 = henc[a2], v3 = henc[a3];
            float4 p0 = lpw[j2+0], p1 = lpw[j2+1], p2 = lpw[j2+2], p3 = lpw[j2+3];
            acc.x += p0.x*v0 + p1.x*v1 + p2.x*v2 + p3.x*v3;
            acc.y += p0.y*v0 + p1.y*v1 + p2.y*v2 + p3.y*v3;
            acc.z += p0.z*v0 + p1.z*v1 + p2.z*v2 + p3.z*v3;
            acc.w += p0.w*v0 + p1.w*v1 + p2.w*v2 + p3.w*v3;
        }
        for (; j2 < cnt; ++j2) {
            float v = henc[lsw[j2] * 64 + lane];
            float4 pj = lpw[j2];
            acc.x += pj.x * v; acc.y += pj.y * v;
            acc.z += pj.z * v; acc.w += pj.w * v;
        }
    }
    float4 r;
    r.x = acc.x / (l.x + 1e-16f);
    r.y = acc.y / (l.y + 1e-16f);
    r.z = acc.z / (l.z + 1e-16f);
    r.w = acc.w / (l.w + 1e-16f);
    *(float4*)(agg + (size_t)n * 256 + lane * 4) = r;   // agg[n][k*4+h]
}

// ---------------- fused GEMM1+ELU+GEMM2+alpha2: 16 nodes/block, 2D register tiles ----------------
// GEMM1: wave = head h; lane owns 4m x 4q. Per k: 1 ds_read_b128 + 1 global float4 -> 16 FMA.
// GEMM2: thread owns 1m x 4c. Per k: 1 ds_read_b32 + 1 global float4 -> 4 FMA.
__global__ __launch_bounds__(256, 8) void gat1_finish_kernel(
    const float* __restrict__ agg, const float* __restrict__ g1w, const float* __restrict__ g1b,
    const float* __restrict__ g2w, const float* __restrict__ g2as, const float* __restrict__ g2ad,
    float* __restrict__ h2, float* __restrict__ as2, float* __restrict__ ad2) {
    __shared__ float s_buf[256 * 20];   // 20KB: phase1 a1[idx=k*4+h][m], phase2 vT[q][m]
    int tid = threadIdx.x;
    int node0 = blockIdx.x * 16;        // 3125 blocks * 16 = 50000 exactly
    for (int i = tid; i < 4096; i += 256) {
        int m = i >> 8, idx = i & 255;
        s_buf[idx * 20 + m] = agg[(size_t)node0 * 256 + i];
    }
    __syncthreads();
    int lane = tid & 63;
    int h = tid >> 6;                   // wave id == head
    int q0 = h * 64 + (lane & 15) * 4;  // output column group
    int mg = (lane >> 4) * 4;           // node sub-tile
    float acc1[4][4];
    #pragma unroll
    for (int i = 0; i < 4; ++i)
        #pragma unroll
        for (int j = 0; j < 4; ++j) acc1[i][j] = 0.f;
    #pragma unroll 4
    for (int k = 0; k < 64; ++k) {
        float4 av = *(const float4*)(s_buf + (k * 4 + h) * 20 + mg);
        float4 wv = *(const float4*)(g1w + k * 256 + q0);
        float a4[4] = {av.x, av.y, av.z, av.w};
        float w4[4] = {wv.x, wv.y, wv.z, wv.w};
        #pragma unroll
        for (int i = 0; i < 4; ++i)
            #pragma unroll
            for (int j = 0; j < 4; ++j) acc1[i][j] += a4[i] * w4[j];
    }
    __syncthreads();   // done reading a1; reuse buffer as vT[q][m]
    #pragma unroll
    for (int j = 0; j < 4; ++j) {
        float b = g1b[q0 + j];
        float4 v;
        float t0 = acc1[0][j] + b; v.x = t0 > 0.f ? t0 : expm1f(t0);
        float t1 = acc1[1][j] + b; v.y = t1 > 0.f ? t1 : expm1f(t1);
        float t2 = acc1[2][j] + b; v.z = t2 > 0.f ? t2 : expm1f(t2);
        float t3 = acc1[3][j] + b; v.w = t3 > 0.f ? t3 : expm1f(t3);
        *(float4*)(s_buf + (q0 + j) * 20 + mg) = v;
    }
    __syncthreads();
    // GEMM2: h2[m][c] = sum_k vT[k][m] * g2w[k*64+c]
    int m = tid >> 4;                   // 0..15
    int c0 = (tid & 15) * 4;
    float acc2[4] = {0.f, 0.f, 0.f, 0.f};
    #pragma unroll 8
    for (int k = 0; k < 256; ++k) {
        float vm = s_buf[k * 20 + m];
        float4 wv = *(const float4*)(g2w + k * 64 + c0);
        acc2[0] += vm * wv.x;
        acc2[1] += vm * wv.y;
        acc2[2] += vm * wv.z;
        acc2[3] += vm * wv.w;
    }
    int n = node0 + m;
    *(float4*)(h2 + (size_t)n * 64 + c0) = make_float4(acc2[0], acc2[1], acc2[2], acc2[3]);
    // fused alpha2: reduce over the head's 16 channels (4 threads x 4 c each)
    float vs = acc2[0] * g2as[c0] + acc2[1] * g2as[c0+1] + acc2[2] * g2as[c0+2] + acc2[3] * g2as[c0+3];
    float vd = acc2[0] * g2ad[c0] + acc2[1] * g2ad[c0+1] + acc2[2] * g2ad[c0+2] + acc2[3] * g2ad[c0+3];
    vs += __shfl_xor(vs, 1); vs += __shfl_xor(vs, 2);
    vd += __shfl_xor(vd, 1); vd += __shfl_xor(vd, 2);
    if ((tid & 3) == 0) {
        int hh = (tid & 15) >> 2;
        as2[n * 4 + hh] = vs;
        ad2[n * 4 + hh] = vd;
    }
}

// ---------------- GAT2 aggregate, single-pass softmax ----------------
__global__ __launch_bounds__(256) void aggregate2_kernel(
    const int* __restrict__ row, const int* __restrict__ csr_src,
    const float* __restrict__ as, const float* __restrict__ ad,
    const float* __restrict__ h, float* __restrict__ out) {
    int wslot = threadIdx.x >> 6;
    int lane  = threadIdx.x & 63;
    int n = blockIdx.x * 4 + wslot;
    __shared__ int    ls[4][64];
    __shared__ float4 lp4[4][64];
    if (n >= N_NODES) return;
    int base = row[n];
    int deg  = row[n + 1] - base;
    int head = lane >> 4;
    float4 add = *(const float4*)(ad + n * 4);

    float4 l = make_float4(0.f, 0.f, 0.f, 0.f);
    float acc = 0.f;
    for (int c0 = 0; c0 < deg; c0 += 64) {
        int j = c0 + lane;
        int s = 0;
        float4 p = make_float4(0.f, 0.f, 0.f, 0.f);
        if (j < deg) {
            s = csr_src[base + j];
            float4 a = *(const float4*)(as + s * 4);
            p.x = __expf(lrelu(a.x + add.x));
            p.y = __expf(lrelu(a.y + add.y));
            p.z = __expf(lrelu(a.z + add.z));
            p.w = __expf(lrelu(a.w + add.w));
        }
        ls[wslot][lane] = s;
        lp4[wslot][lane] = p;
        float4 t = p;
        #pragma unroll
        for (int off = 32; off > 0; off >>= 1) {
            t.x += __shfl_xor(t.x, off);
            t.y += __shfl_xor(t.y, off);
            t.z += __shfl_xor(t.z, off);
            t.w += __shfl_xor(t.w, off);
        }
        l.x += t.x; l.y += t.y; l.z += t.z; l.w += t.w;
        int cnt = min(64, deg - c0);
        const int*   lsw = ls[wslot];
        const float* lpf = (const float*)lp4[wslot];
        int j2 = 0;
        for (; j2 + 4 <= cnt; j2 += 4) {
            int a0 = lsw[j2+0] * 64 + lane;
            int a1 = lsw[j2+1] * 64 + lane;
            int a2 = lsw[j2+2] * 64 + lane;
            int a3 = lsw[j2+3] * 64 + lane;
            float v0 = h[a0], v1 = h[a1], v2 = h[a2], v3 = h[a3];
            float p0 = lpf[(j2+0) * 4 + head];
            float p1 = lpf[(j2+1) * 4 + head];
            float p2 = lpf[(j2+2) * 4 + head];
            float p3 = lpf[(j2+3) * 4 + head];
            acc += p0*v0 + p1*v1 + p2*v2 + p3*v3;
        }
        for (; j2 < cnt; ++j2) {
            acc += lpf[j2 * 4 + head] * h[lsw[j2] * 64 + lane];
        }
    }
    float lh = (head == 0) ? l.x : (head == 1) ? l.y : (head == 2) ? l.z : l.w;
    out[(size_t)n * 64 + lane] = acc / (lh + 1e-16f);
}

// ---------------- decoder: 32 nodes/block, w1 in LDS ----------------
__global__ __launch_bounds__(256) void decoder32_kernel(
    const float* __restrict__ hin, const float* __restrict__ gb,
    const float* __restrict__ w1, const float* __restrict__ b1,
    const float* __restrict__ w2, const float* __restrict__ b2, float* __restrict__ out) {
    __shared__ float s_w1[4096];
    __shared__ float s_w2[256];
    __shared__ float s_h[32][64];
    __shared__ float s_t[32][64];
    int tid = threadIdx.x;
    int node0 = blockIdx.x * 32;
    for (int i = tid; i < 4096; i += 256) s_w1[i] = w1[i];
    if (tid < 256) s_w2[tid] = w2[tid];
    for (int i = tid; i < 2048; i += 256) {
        int nn = i >> 6, k = i & 63;
        int node = node0 + nn;
        s_h[nn][k] = (node < N_NODES ? hin[(size_t)node * 64 + k] : 0.f) + gb[k];
    }
    __syncthreads();
    int c = tid & 63;
    int mg = tid >> 6;
    float b1c = b1[c];
    float acc[8];
    #pragma unroll
    for (int m = 0; m < 8; ++m) acc[m] = b1c;
    #pragma unroll 4
    for (int k = 0; k < 64; ++k) {
        float w = s_w1[k * 64 + c];
        #pragma unroll
        for (int m = 0; m < 8; ++m) acc[m] += s_h[mg * 8 + m][k] * w;
    }
    #pragma unroll
    for (int m = 0; m < 8; ++m) s_t[mg * 8 + m][c] = fmaxf(acc[m], 0.f);
    __syncthreads();
    if (tid < 128) {
        int m = tid >> 2, j = tid & 3;
        int node = node0 + m;
        if (node < N_NODES) {
            float a = b2[j];
            #pragma unroll 16
            for (int k = 0; k < 64; ++k) a += s_t[m][k] * s_w2[k * 4 + j];
            out[node * 4 + j] = a;
        }
    }
}

extern "C" void kernel_launch(void* const* d_in, const int* in_sizes, int n_in,
                              void* d_out, int out_size, void* d_ws, size_t ws_size,
                              hipStream_t stream) {
    const float* x      = (const float*)d_in[0];
    const int*   ei     = (const int*)d_in[1];
    const float* enc_w1 = (const float*)d_in[2];
    const float* enc_b1 = (const float*)d_in[3];
    const float* enc_w2 = (const float*)d_in[4];
    const float* enc_b2 = (const float*)d_in[5];
    const float* g1_w   = (const float*)d_in[6];
    const float* g1_as  = (const float*)d_in[7];
    const float* g1_ad  = (const float*)d_in[8];
    const float* g1_b   = (const float*)d_in[9];
    const float* g2_w   = (const float*)d_in[10];
    const float* g2_as  = (const float*)d_in[11];
    const float* g2_ad  = (const float*)d_in[12];
    const float* g2_b   = (const float*)d_in[13];
    const float* dec_w1 = (const float*)d_in[14];
    const float* dec_b1 = (const float*)d_in[15];
    const float* dec_w2 = (const float*)d_in[16];
    const float* dec_b2 = (const float*)d_in[17];

    const int N = N_NODES, ET = ET_EDGES;

    // workspace layout (floats)
    float* ws   = (float*)d_ws;
    float* henc = ws;                        //  3,200,000
    float* agg  = ws + 3200000;              // 12,800,000
    float* h2   = ws + 16000000;             //  3,200,000
    float* out2 = ws + 19200000;             //  3,200,000
    float* as1  = ws + 22400000;             //    200,000
    float* ad1  = as1 + 200000;
    float* as2  = ad1 + 200000;
    float* ad2  = as2 + 200000;
    float* wsf  = ad2 + 200000;              // 256
    float* wdf  = wsf + 256;                 // 256
    int*   ib      = (int*)(ws + 23201024);
    int*   deg     = ib;                     // 50,001
    int*   rowp    = ib + 50004;             // 50,001
    int*   cursor  = ib + 100008;            // 50,001
    int*   bsum    = ib + 150012;            // 64
    int*   boff    = ib + 150076;            // 64
    int*   csr_src = ib + 150140;            // 850,000

    // CSR build
    hipMemsetAsync(deg, 0, (size_t)N * sizeof(int), stream);
    count_kernel<<<(ET + 255) / 256, 256, 0, stream>>>(ei, deg);
    scanA_kernel<<<NBLK, 1024, 0, stream>>>(deg, rowp, bsum);
    scanB_kernel<<<1, 64, 0, stream>>>(bsum, boff, rowp);
    scanC_kernel<<<(N + 255) / 256, 256, 0, stream>>>(rowp, boff, cursor);
    scatter_kernel<<<(ET + 255) / 256, 256, 0, stream>>>(ei, cursor, csr_src);

    // attention-vector fold + encoder (with fused alpha1)
    fold1_kernel<<<1, 256, 0, stream>>>(g1_w, g1_as, g1_ad, wsf, wdf);
    encoder32_kernel<<<(N + 31) / 32, 256, 0, stream>>>(x, enc_w1, enc_b1, enc_w2, enc_b2,
                                                        wsf, wdf, henc, as1, ad1);

    // GAT1: aggregate in henc-domain, then fused GEMM+ELU+GEMM+alpha2
    aggregate1_kernel<<<(N + 3) / 4, 256, 0, stream>>>(rowp, csr_src, as1, ad1, henc, agg);
    gat1_finish_kernel<<<N / 16, 256, 0, stream>>>(agg, g1_w, g1_b, g2_w, g2_as, g2_ad,
                                                   h2, as2, ad2);

    // GAT2
    aggregate2_kernel<<<(N + 3) / 4, 256, 0, stream>>>(rowp, csr_src, as2, ad2, h2, out2);

    decoder32_kernel<<<(N + 31) / 32, 256, 0, stream>>>(out2, g2_b, dec_w1, dec_b1, dec_w2, dec_b2, (float*)d_out);
}

// Round 8
// 402.950 us; speedup vs baseline: 1.1007x; 1.1007x over previous
//
#include <hip/hip_runtime.h>
#include <hip/hip_bf16.h>

#define N_NODES 50000
#define N_EDGES 800000
#define ET_EDGES 850000   // + self loops
#define HEADS 4
#define NBLK 49           // ceil(N_NODES/1024)

__device__ __forceinline__ float lrelu(float v) { return v > 0.f ? v : 0.2f * v; }

__device__ __forceinline__ void edge_sd(const int* __restrict__ ei, int e, int& s, int& d) {
    if (e < N_EDGES) { s = ei[e]; d = ei[N_EDGES + e]; }
    else { s = d = e - N_EDGES; }
}

// ---------------- CSR build ----------------
__global__ __launch_bounds__(256) void count_kernel(const int* __restrict__ ei, int* __restrict__ deg) {
    int e = blockIdx.x * 256 + threadIdx.x;
    if (e >= ET_EDGES) return;
    int s, d; edge_sd(ei, e, s, d);
    atomicAdd(deg + d, 1);
}

__global__ __launch_bounds__(1024) void scanA_kernel(const int* __restrict__ deg,
                                                     int* __restrict__ rowp, int* __restrict__ bsum) {
    __shared__ int s_wt[16];
    __shared__ int s_we[16];
    int tid = threadIdx.x;
    int wid = tid >> 6, lane = tid & 63;
    int i = blockIdx.x * 1024 + tid;
    int v = (i < N_NODES) ? deg[i] : 0;
    int x = v;
    #pragma unroll
    for (int off = 1; off < 64; off <<= 1) {
        int t = __shfl_up(x, off);
        if (lane >= off) x += t;
    }
    if (lane == 63) s_wt[wid] = x;
    __syncthreads();
    if (tid < 16) {
        int wv = s_wt[tid];
        int y = wv;
        #pragma unroll
        for (int off = 1; off < 16; off <<= 1) {
            int t = __shfl_up(y, off);
            if (tid >= off) y += t;
        }
        s_we[tid] = y - wv;
    }
    __syncthreads();
    int excl = x - v + s_we[wid];
    if (i < N_NODES) rowp[i] = excl;
    if (tid == 1023) bsum[blockIdx.x] = excl + v;
}

__global__ __launch_bounds__(64) void scanB_kernel(const int* __restrict__ bsum,
                                                   int* __restrict__ boff, int* __restrict__ rowp) {
    int lane = threadIdx.x;
    int v = (lane < NBLK) ? bsum[lane] : 0;
    int x = v;
    #pragma unroll
    for (int off = 1; off < 64; off <<= 1) {
        int t = __shfl_up(x, off);
        if (lane >= off) x += t;
    }
    if (lane < NBLK) boff[lane] = x - v;
    if (lane == NBLK - 1) rowp[N_NODES] = x;
}

__global__ __launch_bounds__(256) void scanC_kernel(int* __restrict__ rowp,
                                                    const int* __restrict__ boff, int* __restrict__ cursor) {
    int i = blockIdx.x * 256 + threadIdx.x;
    if (i >= N_NODES) return;
    int v = rowp[i] + boff[i >> 10];
    rowp[i] = v;
    cursor[i] = v;
}

__global__ __launch_bounds__(256) void scatter_kernel(const int* __restrict__ ei,
                                                      int* __restrict__ cursor, int* __restrict__ csr_src) {
    int e = blockIdx.x * 256 + threadIdx.x;
    if (e >= ET_EDGES) return;
    int s, d; edge_sd(ei, e, s, d);
    int pos = atomicAdd(cursor + d, 1);
    csr_src[pos] = s;
}

// ---------------- fold attention vectors through g1_w ----------------
__global__ __launch_bounds__(256) void fold1_kernel(
    const float* __restrict__ g1w, const float* __restrict__ g1as, const float* __restrict__ g1ad,
    float* __restrict__ wsf, float* __restrict__ wdf) {
    int tid = threadIdx.x;       // tid = h*64+k
    int h = tid >> 6, k = tid & 63;
    float as_acc = 0.f, ad_acc = 0.f;
    #pragma unroll 8
    for (int c = 0; c < 64; ++c) {
        float w = g1w[k * 256 + h * 64 + c];
        as_acc += w * g1as[h * 64 + c];
        ad_acc += w * g1ad[h * 64 + c];
    }
    wsf[tid] = as_acc;
    wdf[tid] = ad_acc;
}

// ---------------- encoder (32 nodes/block) + fused alpha1 ----------------
__global__ __launch_bounds__(256) void encoder32_kernel(
    const float* __restrict__ x, const float* __restrict__ w1, const float* __restrict__ b1,
    const float* __restrict__ w2, const float* __restrict__ b2,
    const float* __restrict__ wsf, const float* __restrict__ wdf,
    float* __restrict__ henc, float* __restrict__ as1, float* __restrict__ ad1) {
    __shared__ float s_w2[4096];     // w2[64][64]
    __shared__ float s_t[32][64];
    __shared__ float s_x[32][8];
    __shared__ float s_he[32][65];   // +1 pad
    __shared__ float s_wf[8 * 65];
    int tid = threadIdx.x;
    int node0 = blockIdx.x * 32;
    for (int i = tid; i < 4096; i += 256) s_w2[i] = w2[i];
    for (int i = tid; i < 224; i += 256) {
        int src = node0 * 7 + i;
        s_x[i / 7][i % 7] = (src < N_NODES * 7) ? x[src] : 0.f;
    }
    for (int i = tid; i < 512; i += 256) {
        int g = i >> 6, k = i & 63;
        int h = g & 3;
        s_wf[g * 65 + k] = (g < 4) ? wsf[h * 64 + k] : wdf[h * 64 + k];
    }
    int c = tid & 63;
    int mg = tid >> 6;
    float w1c[7];
    #pragma unroll
    for (int k = 0; k < 7; ++k) w1c[k] = w1[k * 64 + c];
    float b1c = b1[c];
    __syncthreads();
    #pragma unroll
    for (int m = 0; m < 8; ++m) {
        int nn = mg * 8 + m;
        float a = b1c;
        #pragma unroll
        for (int k = 0; k < 7; ++k) a += s_x[nn][k] * w1c[k];
        s_t[nn][c] = fmaxf(a, 0.f);
    }
    __syncthreads();
    float acc[8];
    float b2c = b2[c];
    #pragma unroll
    for (int m = 0; m < 8; ++m) acc[m] = b2c;
    #pragma unroll 4
    for (int k = 0; k < 64; ++k) {
        float w = s_w2[k * 64 + c];
        #pragma unroll
        for (int m = 0; m < 8; ++m) acc[m] += s_t[mg * 8 + m][k] * w;
    }
    #pragma unroll
    for (int m = 0; m < 8; ++m) {
        int nn = mg * 8 + m;
        int node = node0 + nn;
        s_he[nn][c] = acc[m];
        if (node < N_NODES) henc[node * 64 + c] = acc[m];
    }
    __syncthreads();
    {
        int nn = tid >> 3, r = tid & 7;
        int node = node0 + nn;
        const float* wf = s_wf + r * 65;
        float sum = 0.f;
        #pragma unroll 8
        for (int k = 0; k < 64; ++k) sum += s_he[nn][k] * wf[k];
        if (node < N_NODES) {
            int hh = r & 3;
            if (r < 4) as1[node * 4 + hh] = sum;
            else       ad1[node * 4 + hh] = sum;
        }
    }
}

// ---------------- GAT1 aggregation, single-pass softmax ----------------
__global__ __launch_bounds__(256) void aggregate1_kernel(
    const int* __restrict__ row, const int* __restrict__ csr_src,
    const float* __restrict__ as, const float* __restrict__ ad,
    const float* __restrict__ henc, float* __restrict__ agg) {
    int wslot = threadIdx.x >> 6;
    int lane  = threadIdx.x & 63;
    int n = blockIdx.x * 4 + wslot;
    __shared__ int    ls[4][64];
    __shared__ float4 lp4[4][64];
    if (n >= N_NODES) return;
    int base = row[n];
    int deg  = row[n + 1] - base;
    float4 add = *(const float4*)(ad + n * 4);

    float4 l = make_float4(0.f, 0.f, 0.f, 0.f);
    float4 acc = make_float4(0.f, 0.f, 0.f, 0.f);
    for (int c0 = 0; c0 < deg; c0 += 64) {
        int j = c0 + lane;
        int s = 0;
        float4 p = make_float4(0.f, 0.f, 0.f, 0.f);
        if (j < deg) {
            s = csr_src[base + j];
            float4 a = *(const float4*)(as + s * 4);
            p.x = __expf(lrelu(a.x + add.x));
            p.y = __expf(lrelu(a.y + add.y));
            p.z = __expf(lrelu(a.z + add.z));
            p.w = __expf(lrelu(a.w + add.w));
        }
        ls[wslot][lane] = s;
        lp4[wslot][lane] = p;
        float4 t = p;
        #pragma unroll
        for (int off = 32; off > 0; off >>= 1) {
            t.x += __shfl_xor(t.x, off);
            t.y += __shfl_xor(t.y, off);
            t.z += __shfl_xor(t.z, off);
            t.w += __shfl_xor(t.w, off);
        }
        l.x += t.x; l.y += t.y; l.z += t.z; l.w += t.w;
        int cnt = min(64, deg - c0);
        const int*    lsw = ls[wslot];
        const float4* lpw = lp4[wslot];
        int j2 = 0;
        for (; j2 + 4 <= cnt; j2 += 4) {
            int a0 = lsw[j2+0] * 64 + lane;
            int a1 = lsw[j2+1] * 64 + lane;
            int a2 = lsw[j2+2] * 64 + lane;
            int a3 = lsw[j2+3] * 64 + lane;
            float v0 = henc[a0], v1 = henc[a1], v2 = henc[a2], v3 = henc[a3];
            float4 p0 = lpw[j2+0], p1 = lpw[j2+1], p2 = lpw[j2+2], p3 = lpw[j2+3];
            acc.x += p0.x*v0 + p1.x*v1 + p2.x*v2 + p3.x*v3;
            acc.y += p0.y*v0 + p1.y*v1 + p2.y*v2 + p3.y*v3;
            acc.z += p0.z*v0 + p1.z*v1 + p2.z*v2 + p3.z*v3;
            acc.w += p0.w*v0 + p1.w*v1 + p2.w*v2 + p3.w*v3;
        }
        for (; j2 < cnt; ++j2) {
            float v = henc[lsw[j2] * 64 + lane];
            float4 pj = lpw[j2];
            acc.x += pj.x * v; acc.y += pj.y * v;
            acc.z += pj.z * v; acc.w += pj.w * v;
        }
    }
    float4 r;
    r.x = acc.x / (l.x + 1e-16f);
    r.y = acc.y / (l.y + 1e-16f);
    r.z = acc.z / (l.z + 1e-16f);
    r.w = acc.w / (l.w + 1e-16f);
    *(float4*)(agg + (size_t)n * 256 + lane * 4) = r;   // agg[n][k*4+h]
}

// ---------------- fused GEMM1+ELU+GEMM2+alpha2: 32 nodes/block, ALL operands in LDS ----------------
// LDS: s_a (36 KB) holds agg[idx][m] -> vT[k2][m] -> partials; s_w (16 KB) holds weight chunks.
// GEMM1: thread = 4q x 8m; per k: 2 ds_read_b128 (a) + 1 ds_read_b128 (w) -> 32 FMA.
// GEMM2: thread = 4c x 8m x k-split4; same 3:32 ratio; register partials reduced via LDS at end.
__global__ __launch_bounds__(256, 3) void gat1_finish_kernel(
    const float* __restrict__ agg, const float* __restrict__ g1w, const float* __restrict__ g1b,
    const float* __restrict__ g2w, const float* __restrict__ g2as, const float* __restrict__ g2ad,
    float* __restrict__ h2, float* __restrict__ as2, float* __restrict__ ad2) {
    __shared__ float s_a[256 * 36];   // 36 KB
    __shared__ float s_w[4096];       // 16 KB
    int tid = threadIdx.x;
    int node0 = blockIdx.x * 32;
    // stage agg (32 nodes x 256) -> s_a[idx][m], stride 36
    for (int i = tid; i < 32 * 256; i += 256) {
        int m = i >> 8, idx = i & 255;
        int gi = node0 * 256 + i;
        s_a[idx * 36 + m] = (gi < N_NODES * 256) ? agg[gi] : 0.f;
    }
    // ---- GEMM1: out1[m][q] = sum_k a[(k*4+h)][m] * g1w[k][q] ----
    int q0 = (tid & 63) * 4;
    int h  = (tid & 63) >> 4;
    int mg = (tid >> 6) * 8;
    float acc[8][4];
    #pragma unroll
    for (int i = 0; i < 8; ++i)
        #pragma unroll
        for (int j = 0; j < 4; ++j) acc[i][j] = 0.f;
    for (int kc = 0; kc < 4; ++kc) {
        __syncthreads();   // staging done (kc=0) / prev chunk reads done
        for (int i = tid * 4; i < 4096; i += 1024)
            *(float4*)(s_w + i) = *(const float4*)(g1w + kc * 4096 + i);
        __syncthreads();
        #pragma unroll 4
        for (int kk = 0; kk < 16; ++kk) {
            int k = kc * 16 + kk;
            const float* ap = s_a + (k * 4 + h) * 36 + mg;
            float4 a0 = *(const float4*)ap;
            float4 a1 = *(const float4*)(ap + 4);
            float4 w = *(const float4*)(s_w + kk * 256 + q0);
            float av[8] = {a0.x, a0.y, a0.z, a0.w, a1.x, a1.y, a1.z, a1.w};
            float wv[4] = {w.x, w.y, w.z, w.w};
            #pragma unroll
            for (int i = 0; i < 8; ++i)
                #pragma unroll
                for (int j = 0; j < 4; ++j) acc[i][j] += av[i] * wv[j];
        }
    }
    __syncthreads();   // all agg reads done; reuse s_a as vT[k2][m]
    #pragma unroll
    for (int j = 0; j < 4; ++j) {
        float bj = g1b[q0 + j];
        float t[8];
        #pragma unroll
        for (int i = 0; i < 8; ++i) {
            float v = acc[i][j] + bj;
            t[i] = v > 0.f ? v : expm1f(v);   // ELU
        }
        *(float4*)(s_a + (q0 + j) * 36 + mg)     = make_float4(t[0], t[1], t[2], t[3]);
        *(float4*)(s_a + (q0 + j) * 36 + mg + 4) = make_float4(t[4], t[5], t[6], t[7]);
    }
    // ---- GEMM2: h2[m][c] = sum_k vT[k][m] * g2w[k][c] ----
    int c0 = (tid & 15) * 4;
    int m0 = ((tid >> 4) & 3) * 8;
    int ks = tid >> 6;
    float acc2[8][4];
    #pragma unroll
    for (int i = 0; i < 8; ++i)
        #pragma unroll
        for (int j = 0; j < 4; ++j) acc2[i][j] = 0.f;
    for (int kc = 0; kc < 4; ++kc) {
        __syncthreads();   // vT writes done (kc=0) / prev chunk reads done
        for (int i = tid * 4; i < 4096; i += 1024)
            *(float4*)(s_w + i) = *(const float4*)(g2w + kc * 4096 + i);
        __syncthreads();
        #pragma unroll 4
        for (int kk = 0; kk < 16; ++kk) {
            int kl = ks * 16 + kk;        // local k within 64-k chunk
            int k  = kc * 64 + kl;        // global k2 index into vT
            const float* ap = s_a + k * 36 + m0;
            float4 a0 = *(const float4*)ap;
            float4 a1 = *(const float4*)(ap + 4);
            float4 w = *(const float4*)(s_w + kl * 64 + c0);
            float av[8] = {a0.x, a0.y, a0.z, a0.w, a1.x, a1.y, a1.z, a1.w};
            float wv[4] = {w.x, w.y, w.z, w.w};
            #pragma unroll
            for (int i = 0; i < 8; ++i)
                #pragma unroll
                for (int j = 0; j < 4; ++j) acc2[i][j] += av[i] * wv[j];
        }
    }
    __syncthreads();   // all vT reads done; reuse s_a for partials [ks][m][c]
    #pragma unroll
    for (int i = 0; i < 8; ++i)
        *(float4*)(s_a + ks * 2048 + (m0 + i) * 64 + c0) =
            make_float4(acc2[i][0], acc2[i][1], acc2[i][2], acc2[i][3]);
    __syncthreads();
    int o = tid * 8;          // 0..2047
    int m = o >> 6;
    int cb = o & 63;          // (tid&7)*8
    float s[8];
    #pragma unroll
    for (int u = 0; u < 8; ++u) s[u] = 0.f;
    #pragma unroll
    for (int k4 = 0; k4 < 4; ++k4) {
        float4 r0 = *(const float4*)(s_a + k4 * 2048 + o);
        float4 r1 = *(const float4*)(s_a + k4 * 2048 + o + 4);
        s[0] += r0.x; s[1] += r0.y; s[2] += r0.z; s[3] += r0.w;
        s[4] += r1.x; s[5] += r1.y; s[6] += r1.z; s[7] += r1.w;
    }
    int n = node0 + m;
    float vs = 0.f, vd = 0.f;
    #pragma unroll
    for (int u = 0; u < 8; ++u) {
        vs += s[u] * g2as[cb + u];
        vd += s[u] * g2ad[cb + u];
    }
    vs += __shfl_xor(vs, 1);
    vd += __shfl_xor(vd, 1);
    if (n < N_NODES) {
        *(float4*)(h2 + (size_t)n * 64 + cb)     = make_float4(s[0], s[1], s[2], s[3]);
        *(float4*)(h2 + (size_t)n * 64 + cb + 4) = make_float4(s[4], s[5], s[6], s[7]);
        if ((tid & 1) == 0) {
            int hh = cb >> 4;
            as2[n * 4 + hh] = vs;
            ad2[n * 4 + hh] = vd;
        }
    }
}

// ---------------- GAT2 aggregate, single-pass softmax ----------------
__global__ __launch_bounds__(256) void aggregate2_kernel(
    const int* __restrict__ row, const int* __restrict__ csr_src,
    const float* __restrict__ as, const float* __restrict__ ad,
    const float* __restrict__ h, float* __restrict__ out) {
    int wslot = threadIdx.x >> 6;
    int lane  = threadIdx.x & 63;
    int n = blockIdx.x * 4 + wslot;
    __shared__ int    ls[4][64];
    __shared__ float4 lp4[4][64];
    if (n >= N_NODES) return;
    int base = row[n];
    int deg  = row[n + 1] - base;
    int head = lane >> 4;
    float4 add = *(const float4*)(ad + n * 4);

    float4 l = make_float4(0.f, 0.f, 0.f, 0.f);
    float acc = 0.f;
    for (int c0 = 0; c0 < deg; c0 += 64) {
        int j = c0 + lane;
        int s = 0;
        float4 p = make_float4(0.f, 0.f, 0.f, 0.f);
        if (j < deg) {
            s = csr_src[base + j];
            float4 a = *(const float4*)(as + s * 4);
            p.x = __expf(lrelu(a.x + add.x));
            p.y = __expf(lrelu(a.y + add.y));
            p.z = __expf(lrelu(a.z + add.z));
            p.w = __expf(lrelu(a.w + add.w));
        }
        ls[wslot][lane] = s;
        lp4[wslot][lane] = p;
        float4 t = p;
        #pragma unroll
        for (int off = 32; off > 0; off >>= 1) {
            t.x += __shfl_xor(t.x, off);
            t.y += __shfl_xor(t.y, off);
            t.z += __shfl_xor(t.z, off);
            t.w += __shfl_xor(t.w, off);
        }
        l.x += t.x; l.y += t.y; l.z += t.z; l.w += t.w;
        int cnt = min(64, deg - c0);
        const int*   lsw = ls[wslot];
        const float* lpf = (const float*)lp4[wslot];
        int j2 = 0;
        for (; j2 + 4 <= cnt; j2 += 4) {
            int a0 = lsw[j2+0] * 64 + lane;
            int a1 = lsw[j2+1] * 64 + lane;
            int a2 = lsw[j2+2] * 64 + lane;
            int a3 = lsw[j2+3] * 64 + lane;
            float v0 = h[a0], v1 = h[a1], v2 = h[a2], v3 = h[a3];
            float p0 = lpf[(j2+0) * 4 + head];
            float p1 = lpf[(j2+1) * 4 + head];
            float p2 = lpf[(j2+2) * 4 + head];
            float p3 = lpf[(j2+3) * 4 + head];
            acc += p0*v0 + p1*v1 + p2*v2 + p3*v3;
        }
        for (; j2 < cnt; ++j2) {
            acc += lpf[j2 * 4 + head] * h[lsw[j2] * 64 + lane];
        }
    }
    float lh = (head == 0) ? l.x : (head == 1) ? l.y : (head == 2) ? l.z : l.w;
    out[(size_t)n * 64 + lane] = acc / (lh + 1e-16f);
}

// ---------------- decoder: 32 nodes/block, w1 in LDS ----------------
__global__ __launch_bounds__(256) void decoder32_kernel(
    const float* __restrict__ hin, const float* __restrict__ gb,
    const float* __restrict__ w1, const float* __restrict__ b1,
    const float* __restrict__ w2, const float* __restrict__ b2, float* __restrict__ out) {
    __shared__ float s_w1[4096];
    __shared__ float s_w2[256];
    __shared__ float s_h[32][64];
    __shared__ float s_t[32][64];
    int tid = threadIdx.x;
    int node0 = blockIdx.x * 32;
    for (int i = tid; i < 4096; i += 256) s_w1[i] = w1[i];
    if (tid < 256) s_w2[tid] = w2[tid];
    for (int i = tid; i < 2048; i += 256) {
        int nn = i >> 6, k = i & 63;
        int node = node0 + nn;
        s_h[nn][k] = (node < N_NODES ? hin[(size_t)node * 64 + k] : 0.f) + gb[k];
    }
    __syncthreads();
    int c = tid & 63;
    int mg = tid >> 6;
    float b1c = b1[c];
    float acc[8];
    #pragma unroll
    for (int m = 0; m < 8; ++m) acc[m] = b1c;
    #pragma unroll 4
    for (int k = 0; k < 64; ++k) {
        float w = s_w1[k * 64 + c];
        #pragma unroll
        for (int m = 0; m < 8; ++m) acc[m] += s_h[mg * 8 + m][k] * w;
    }
    #pragma unroll
    for (int m = 0; m < 8; ++m) s_t[mg * 8 + m][c] = fmaxf(acc[m], 0.f);
    __syncthreads();
    if (tid < 128) {
        int m = tid >> 2, j = tid & 3;
        int node = node0 + m;
        if (node < N_NODES) {
            float a = b2[j];
            #pragma unroll 16
            for (int k = 0; k < 64; ++k) a += s_t[m][k] * s_w2[k * 4 + j];
            out[node * 4 + j] = a;
        }
    }
}

extern "C" void kernel_launch(void* const* d_in, const int* in_sizes, int n_in,
                              void* d_out, int out_size, void* d_ws, size_t ws_size,
                              hipStream_t stream) {
    const float* x      = (const float*)d_in[0];
    const int*   ei     = (const int*)d_in[1];
    const float* enc_w1 = (const float*)d_in[2];
    const float* enc_b1 = (const float*)d_in[3];
    const float* enc_w2 = (const float*)d_in[4];
    const float* enc_b2 = (const float*)d_in[5];
    const float* g1_w   = (const float*)d_in[6];
    const float* g1_as  = (const float*)d_in[7];
    const float* g1_ad  = (const float*)d_in[8];
    const float* g1_b   = (const float*)d_in[9];
    const float* g2_w   = (const float*)d_in[10];
    const float* g2_as  = (const float*)d_in[11];
    const float* g2_ad  = (const float*)d_in[12];
    const float* g2_b   = (const float*)d_in[13];
    const float* dec_w1 = (const float*)d_in[14];
    const float* dec_b1 = (const float*)d_in[15];
    const float* dec_w2 = (const float*)d_in[16];
    const float* dec_b2 = (const float*)d_in[17];

    const int N = N_NODES, ET = ET_EDGES;

    // workspace layout (floats)
    float* ws   = (float*)d_ws;
    float* henc = ws;                        //  3,200,000
    float* agg  = ws + 3200000;              // 12,800,000
    float* h2   = ws + 16000000;             //  3,200,000
    float* out2 = ws + 19200000;             //  3,200,000
    float* as1  = ws + 22400000;             //    200,000
    float* ad1  = as1 + 200000;
    float* as2  = ad1 + 200000;
    float* ad2  = as2 + 200000;
    float* wsf  = ad2 + 200000;              // 256
    float* wdf  = wsf + 256;                 // 256
    int*   ib      = (int*)(ws + 23201024);
    int*   deg     = ib;                     // 50,001
    int*   rowp    = ib + 50004;             // 50,001
    int*   cursor  = ib + 100008;            // 50,001
    int*   bsum    = ib + 150012;            // 64
    int*   boff    = ib + 150076;            // 64
    int*   csr_src = ib + 150140;            // 850,000

    // CSR build
    hipMemsetAsync(deg, 0, (size_t)N * sizeof(int), stream);
    count_kernel<<<(ET + 255) / 256, 256, 0, stream>>>(ei, deg);
    scanA_kernel<<<NBLK, 1024, 0, stream>>>(deg, rowp, bsum);
    scanB_kernel<<<1, 64, 0, stream>>>(bsum, boff, rowp);
    scanC_kernel<<<(N + 255) / 256, 256, 0, stream>>>(rowp, boff, cursor);
    scatter_kernel<<<(ET + 255) / 256, 256, 0, stream>>>(ei, cursor, csr_src);

    // attention-vector fold + encoder (with fused alpha1)
    fold1_kernel<<<1, 256, 0, stream>>>(g1_w, g1_as, g1_ad, wsf, wdf);
    encoder32_kernel<<<(N + 31) / 32, 256, 0, stream>>>(x, enc_w1, enc_b1, enc_w2, enc_b2,
                                                        wsf, wdf, henc, as1, ad1);

    // GAT1: aggregate in henc-domain, then fused GEMM+ELU+GEMM+alpha2 (all-LDS operands)
    aggregate1_kernel<<<(N + 3) / 4, 256, 0, stream>>>(rowp, csr_src, as1, ad1, henc, agg);
    gat1_finish_kernel<<<(N + 31) / 32, 256, 0, stream>>>(agg, g1_w, g1_b, g2_w, g2_as, g2_ad,
                                                          h2, as2, ad2);

    // GAT2
    aggregate2_kernel<<<(N + 3) / 4, 256, 0, stream>>>(rowp, csr_src, as2, ad2, h2, out2);

    decoder32_kernel<<<(N + 31) / 32, 256, 0, stream>>>(out2, g2_b, dec_w1, dec_b1, dec_w2, dec_b2, (float*)d_out);
}

// Round 9
// 374.579 us; speedup vs baseline: 1.1841x; 1.0757x over previous
//
#include <hip/hip_runtime.h>
#include <hip/hip_bf16.h>

#define N_NODES 50000
#define N_EDGES 800000
#define ET_EDGES 850000   // + self loops
#define HEADS 4
#define NBLK 49           // ceil(N_NODES/1024)
#define CNT_BLOCKS 3321   // ceil(ET_EDGES/256)
#define ENC_BLOCKS 1563   // ceil(N_NODES/32)

__device__ __forceinline__ float lrelu(float v) { return v > 0.f ? v : 0.2f * v; }

__device__ __forceinline__ void edge_sd(const int* __restrict__ ei, int e, int& s, int& d) {
    if (e < N_EDGES) { s = ei[e]; d = ei[N_EDGES + e]; }
    else { s = d = e - N_EDGES; }
}

// ---------------- zero deg + fold attention vectors (one dispatch) ----------------
__global__ __launch_bounds__(256) void zerofold_kernel(
    int* __restrict__ deg,
    const float* __restrict__ g1w, const float* __restrict__ g1as, const float* __restrict__ g1ad,
    float* __restrict__ wsf, float* __restrict__ wdf) {
    if (blockIdx.x < 63) {
        for (int i = blockIdx.x * 256 + threadIdx.x; i < N_NODES; i += 63 * 256) deg[i] = 0;
    } else {
        int tid = threadIdx.x;       // tid = h*64+k
        int h = tid >> 6, k = tid & 63;
        float as_acc = 0.f, ad_acc = 0.f;
        #pragma unroll 8
        for (int c = 0; c < 64; ++c) {
            float w = g1w[k * 256 + h * 64 + c];
            as_acc += w * g1as[h * 64 + c];
            ad_acc += w * g1ad[h * 64 + c];
        }
        wsf[tid] = as_acc;
        wdf[tid] = ad_acc;
    }
}

// ---------------- mega: edge count (blocks 0..CNT) + encoder/alpha1 (rest) ----------------
__global__ __launch_bounds__(256) void count_enc_kernel(
    const int* __restrict__ ei, int* __restrict__ deg,
    const float* __restrict__ x, const float* __restrict__ w1, const float* __restrict__ b1,
    const float* __restrict__ w2, const float* __restrict__ b2,
    const float* __restrict__ wsf, const float* __restrict__ wdf,
    float* __restrict__ henc, float* __restrict__ as1, float* __restrict__ ad1) {
    __shared__ float s_w2[4096];
    __shared__ float s_t[32][64];
    __shared__ float s_x[32][8];
    __shared__ float s_he[32][65];
    __shared__ float s_wf[8 * 65];
    if (blockIdx.x < CNT_BLOCKS) {
        int e = blockIdx.x * 256 + threadIdx.x;
        if (e < ET_EDGES) {
            int s, d; edge_sd(ei, e, s, d);
            atomicAdd(deg + d, 1);
        }
        return;
    }
    int tid = threadIdx.x;
    int node0 = (blockIdx.x - CNT_BLOCKS) * 32;
    for (int i = tid; i < 4096; i += 256) s_w2[i] = w2[i];
    for (int i = tid; i < 224; i += 256) {
        int src = node0 * 7 + i;
        s_x[i / 7][i % 7] = (src < N_NODES * 7) ? x[src] : 0.f;
    }
    for (int i = tid; i < 512; i += 256) {
        int g = i >> 6, k = i & 63;
        int h = g & 3;
        s_wf[g * 65 + k] = (g < 4) ? wsf[h * 64 + k] : wdf[h * 64 + k];
    }
    int c = tid & 63;
    int mg = tid >> 6;
    float w1c[7];
    #pragma unroll
    for (int k = 0; k < 7; ++k) w1c[k] = w1[k * 64 + c];
    float b1c = b1[c];
    __syncthreads();
    #pragma unroll
    for (int m = 0; m < 8; ++m) {
        int nn = mg * 8 + m;
        float a = b1c;
        #pragma unroll
        for (int k = 0; k < 7; ++k) a += s_x[nn][k] * w1c[k];
        s_t[nn][c] = fmaxf(a, 0.f);
    }
    __syncthreads();
    float acc[8];
    float b2c = b2[c];
    #pragma unroll
    for (int m = 0; m < 8; ++m) acc[m] = b2c;
    #pragma unroll 4
    for (int k = 0; k < 64; ++k) {
        float w = s_w2[k * 64 + c];
        #pragma unroll
        for (int m = 0; m < 8; ++m) acc[m] += s_t[mg * 8 + m][k] * w;
    }
    #pragma unroll
    for (int m = 0; m < 8; ++m) {
        int nn = mg * 8 + m;
        int node = node0 + nn;
        s_he[nn][c] = acc[m];
        if (node < N_NODES) henc[node * 64 + c] = acc[m];
    }
    __syncthreads();
    {
        int nn = tid >> 3, r = tid & 7;
        int node = node0 + nn;
        const float* wf = s_wf + r * 65;
        float sum = 0.f;
        #pragma unroll 8
        for (int k = 0; k < 64; ++k) sum += s_he[nn][k] * wf[k];
        if (node < N_NODES) {
            int hh = r & 3;
            if (r < 4) as1[node * 4 + hh] = sum;
            else       ad1[node * 4 + hh] = sum;
        }
    }
}

// ---------------- scan phases ----------------
__global__ __launch_bounds__(1024) void scanA_kernel(const int* __restrict__ deg,
                                                     int* __restrict__ rowp, int* __restrict__ bsum) {
    __shared__ int s_wt[16];
    __shared__ int s_we[16];
    int tid = threadIdx.x;
    int wid = tid >> 6, lane = tid & 63;
    int i = blockIdx.x * 1024 + tid;
    int v = (i < N_NODES) ? deg[i] : 0;
    int x = v;
    #pragma unroll
    for (int off = 1; off < 64; off <<= 1) {
        int t = __shfl_up(x, off);
        if (lane >= off) x += t;
    }
    if (lane == 63) s_wt[wid] = x;
    __syncthreads();
    if (tid < 16) {
        int wv = s_wt[tid];
        int y = wv;
        #pragma unroll
        for (int off = 1; off < 16; off <<= 1) {
            int t = __shfl_up(y, off);
            if (tid >= off) y += t;
        }
        s_we[tid] = y - wv;
    }
    __syncthreads();
    int excl = x - v + s_we[wid];
    if (i < N_NODES) rowp[i] = excl;
    if (tid == 1023) bsum[blockIdx.x] = excl + v;
}

__global__ __launch_bounds__(64) void scanB_kernel(const int* __restrict__ bsum,
                                                   int* __restrict__ boff, int* __restrict__ rowp) {
    int lane = threadIdx.x;
    int v = (lane < NBLK) ? bsum[lane] : 0;
    int x = v;
    #pragma unroll
    for (int off = 1; off < 64; off <<= 1) {
        int t = __shfl_up(x, off);
        if (lane >= off) x += t;
    }
    if (lane < NBLK) boff[lane] = x - v;
    if (lane == NBLK - 1) rowp[N_NODES] = x;
}

__global__ __launch_bounds__(256) void scanC_kernel(int* __restrict__ rowp,
                                                    const int* __restrict__ boff, int* __restrict__ cursor) {
    int i = blockIdx.x * 256 + threadIdx.x;
    if (i >= N_NODES) return;
    int v = rowp[i] + boff[i >> 10];
    rowp[i] = v;
    cursor[i] = v;
}

__global__ __launch_bounds__(256) void scatter_kernel(const int* __restrict__ ei,
                                                      int* __restrict__ cursor, int* __restrict__ csr_src) {
    int e = blockIdx.x * 256 + threadIdx.x;
    if (e >= ET_EDGES) return;
    int s, d; edge_sd(ei, e, s, d);
    int pos = atomicAdd(cursor + d, 1);
    csr_src[pos] = s;
}

// ---------------- GAT1 aggregation, single-pass softmax, 8-wide gather ----------------
__global__ __launch_bounds__(256) void aggregate1_kernel(
    const int* __restrict__ row, const int* __restrict__ csr_src,
    const float* __restrict__ as, const float* __restrict__ ad,
    const float* __restrict__ henc, float* __restrict__ agg) {
    int wslot = threadIdx.x >> 6;
    int lane  = threadIdx.x & 63;
    int n = blockIdx.x * 4 + wslot;
    __shared__ int    ls[4][64];
    __shared__ float4 lp4[4][64];
    if (n >= N_NODES) return;
    int base = row[n];
    int deg  = row[n + 1] - base;
    float4 add = *(const float4*)(ad + n * 4);

    float4 l = make_float4(0.f, 0.f, 0.f, 0.f);
    float4 acc = make_float4(0.f, 0.f, 0.f, 0.f);
    for (int c0 = 0; c0 < deg; c0 += 64) {
        int j = c0 + lane;
        int s = 0;
        float4 p = make_float4(0.f, 0.f, 0.f, 0.f);
        if (j < deg) {
            s = csr_src[base + j];
            float4 a = *(const float4*)(as + s * 4);
            p.x = __expf(lrelu(a.x + add.x));
            p.y = __expf(lrelu(a.y + add.y));
            p.z = __expf(lrelu(a.z + add.z));
            p.w = __expf(lrelu(a.w + add.w));
        }
        ls[wslot][lane] = s;
        lp4[wslot][lane] = p;
        float4 t = p;
        #pragma unroll
        for (int off = 32; off > 0; off >>= 1) {
            t.x += __shfl_xor(t.x, off);
            t.y += __shfl_xor(t.y, off);
            t.z += __shfl_xor(t.z, off);
            t.w += __shfl_xor(t.w, off);
        }
        l.x += t.x; l.y += t.y; l.z += t.z; l.w += t.w;
        int cnt = min(64, deg - c0);
        const int*    lsw = ls[wslot];
        const float4* lpw = lp4[wslot];
        int j2 = 0;
        for (; j2 + 8 <= cnt; j2 += 8) {
            float v[8];
            #pragma unroll
            for (int u = 0; u < 8; ++u) v[u] = henc[lsw[j2+u] * 64 + lane];
            #pragma unroll
            for (int u = 0; u < 8; ++u) {
                float4 pj = lpw[j2+u];
                acc.x += pj.x * v[u]; acc.y += pj.y * v[u];
                acc.z += pj.z * v[u]; acc.w += pj.w * v[u];
            }
        }
        for (; j2 + 4 <= cnt; j2 += 4) {
            float v0 = henc[lsw[j2+0] * 64 + lane];
            float v1 = henc[lsw[j2+1] * 64 + lane];
            float v2 = henc[lsw[j2+2] * 64 + lane];
            float v3 = henc[lsw[j2+3] * 64 + lane];
            float4 p0 = lpw[j2+0], p1 = lpw[j2+1], p2 = lpw[j2+2], p3 = lpw[j2+3];
            acc.x += p0.x*v0 + p1.x*v1 + p2.x*v2 + p3.x*v3;
            acc.y += p0.y*v0 + p1.y*v1 + p2.y*v2 + p3.y*v3;
            acc.z += p0.z*v0 + p1.z*v1 + p2.z*v2 + p3.z*v3;
            acc.w += p0.w*v0 + p1.w*v1 + p2.w*v2 + p3.w*v3;
        }
        for (; j2 < cnt; ++j2) {
            float v = henc[lsw[j2] * 64 + lane];
            float4 pj = lpw[j2];
            acc.x += pj.x * v; acc.y += pj.y * v;
            acc.z += pj.z * v; acc.w += pj.w * v;
        }
    }
    float4 r;
    r.x = acc.x / (l.x + 1e-16f);
    r.y = acc.y / (l.y + 1e-16f);
    r.z = acc.z / (l.z + 1e-16f);
    r.w = acc.w / (l.w + 1e-16f);
    *(float4*)(agg + (size_t)n * 256 + lane * 4) = r;   // agg[n][k*4+h]
}

// ---------------- fused GEMM1+ELU+GEMM2+alpha2: 16 nodes/block, 36 KB LDS, 4 blocks/CU ----------------
// s_a (20 KB, stride 20): agg[idx=k*4+h][m] -> vT[q][m] -> partials[ks][m][c]
// s_w (16 KB): streamed weight chunks. Per k-iter/thread: 2 ds_read_b128 -> 16 FMA.
__global__ __launch_bounds__(256, 4) void gat1_finish_kernel(
    const float* __restrict__ agg, const float* __restrict__ g1w, const float* __restrict__ g1b,
    const float* __restrict__ g2w, const float* __restrict__ g2as, const float* __restrict__ g2ad,
    float* __restrict__ h2, float* __restrict__ as2, float* __restrict__ ad2) {
    __shared__ float s_a[256 * 20];
    __shared__ float s_w[4096];
    int tid = threadIdx.x;
    int node0 = blockIdx.x * 16;        // 3125 blocks * 16 = 50000 exactly
    for (int i = tid; i < 4096; i += 256) {
        int m = i >> 8, idx = i & 255;
        s_a[idx * 20 + m] = agg[(size_t)node0 * 256 + i];
    }
    // ---- GEMM1: out1[m][q] = sum_k a[(k*4+h)][m] * g1w[k][q] ----
    int h  = tid >> 6;                  // wave == head (wave-uniform)
    int c0 = (tid & 15) * 4;
    int mg = ((tid >> 4) & 3) * 4;
    int q0 = h * 64 + c0;
    float acc[4][4];
    #pragma unroll
    for (int i = 0; i < 4; ++i)
        #pragma unroll
        for (int j = 0; j < 4; ++j) acc[i][j] = 0.f;
    for (int kc = 0; kc < 4; ++kc) {
        __syncthreads();   // staging done (kc=0) / prev chunk reads done
        for (int i = tid * 4; i < 4096; i += 1024)
            *(float4*)(s_w + i) = *(const float4*)(g1w + kc * 4096 + i);
        __syncthreads();
        #pragma unroll 4
        for (int kk = 0; kk < 16; ++kk) {
            int k = kc * 16 + kk;
            float4 av = *(const float4*)(s_a + (k * 4 + h) * 20 + mg);
            float4 wv = *(const float4*)(s_w + kk * 256 + q0);
            float a4[4] = {av.x, av.y, av.z, av.w};
            float w4[4] = {wv.x, wv.y, wv.z, wv.w};
            #pragma unroll
            for (int i = 0; i < 4; ++i)
                #pragma unroll
                for (int j = 0; j < 4; ++j) acc[i][j] += a4[i] * w4[j];
        }
    }
    __syncthreads();   // all agg reads done; reuse s_a as vT[q][m]
    #pragma unroll
    for (int j = 0; j < 4; ++j) {
        float bj = g1b[q0 + j];
        float4 v;
        float t0 = acc[0][j] + bj; v.x = t0 > 0.f ? t0 : expm1f(t0);
        float t1 = acc[1][j] + bj; v.y = t1 > 0.f ? t1 : expm1f(t1);
        float t2 = acc[2][j] + bj; v.z = t2 > 0.f ? t2 : expm1f(t2);
        float t3 = acc[3][j] + bj; v.w = t3 > 0.f ? t3 : expm1f(t3);
        *(float4*)(s_a + (q0 + j) * 20 + mg) = v;
    }
    // ---- GEMM2: h2[m][c] = sum_k2 vT[k2][m] * g2w[k2][c], k-split 4 ----
    int c2 = (tid & 15) * 4;
    int m0 = ((tid >> 4) & 3) * 4;
    int ks = tid >> 6;
    float acc2[4][4];
    #pragma unroll
    for (int i = 0; i < 4; ++i)
        #pragma unroll
        for (int j = 0; j < 4; ++j) acc2[i][j] = 0.f;
    for (int kc = 0; kc < 4; ++kc) {
        __syncthreads();   // vT writes done (kc=0) / prev chunk reads done
        for (int i = tid * 4; i < 4096; i += 1024)
            *(float4*)(s_w + i) = *(const float4*)(g2w + kc * 4096 + i);
        __syncthreads();
        #pragma unroll 4
        for (int kk = 0; kk < 16; ++kk) {
            int kl = ks * 16 + kk;        // row within 64-row chunk
            int k2 = kc * 64 + kl;
            float4 av = *(const float4*)(s_a + k2 * 20 + m0);
            float4 wv = *(const float4*)(s_w + kl * 64 + c2);
            float a4[4] = {av.x, av.y, av.z, av.w};
            float w4[4] = {wv.x, wv.y, wv.z, wv.w};
            #pragma unroll
            for (int i = 0; i < 4; ++i)
                #pragma unroll
                for (int j = 0; j < 4; ++j) acc2[i][j] += a4[i] * w4[j];
        }
    }
    __syncthreads();   // all vT reads done; reuse s_a for partials [ks][m][c]
    #pragma unroll
    for (int i = 0; i < 4; ++i)
        *(float4*)(s_a + ks * 1024 + (m0 + i) * 64 + c2) =
            make_float4(acc2[i][0], acc2[i][1], acc2[i][2], acc2[i][3]);
    __syncthreads();
    int o = tid * 4;          // 0..1023
    int m = o >> 6;
    int cb = o & 63;
    float4 s = make_float4(0.f, 0.f, 0.f, 0.f);
    #pragma unroll
    for (int k4 = 0; k4 < 4; ++k4) {
        float4 r0 = *(const float4*)(s_a + k4 * 1024 + o);
        s.x += r0.x; s.y += r0.y; s.z += r0.z; s.w += r0.w;
    }
    int n = node0 + m;
    *(float4*)(h2 + (size_t)n * 64 + cb) = s;
    // fused alpha2: head hh = cb>>4; reduce over 4 threads (16 channels)
    float vs = s.x * g2as[cb] + s.y * g2as[cb+1] + s.z * g2as[cb+2] + s.w * g2as[cb+3];
    float vd = s.x * g2ad[cb] + s.y * g2ad[cb+1] + s.z * g2ad[cb+2] + s.w * g2ad[cb+3];
    vs += __shfl_xor(vs, 1); vs += __shfl_xor(vs, 2);
    vd += __shfl_xor(vd, 1); vd += __shfl_xor(vd, 2);
    if ((tid & 3) == 0) {
        int hh = cb >> 4;
        as2[n * 4 + hh] = vs;
        ad2[n * 4 + hh] = vd;
    }
}

// ---------------- GAT2 aggregate, single-pass softmax, 8-wide gather ----------------
__global__ __launch_bounds__(256) void aggregate2_kernel(
    const int* __restrict__ row, const int* __restrict__ csr_src,
    const float* __restrict__ as, const float* __restrict__ ad,
    const float* __restrict__ h, float* __restrict__ out) {
    int wslot = threadIdx.x >> 6;
    int lane  = threadIdx.x & 63;
    int n = blockIdx.x * 4 + wslot;
    __shared__ int    ls[4][64];
    __shared__ float4 lp4[4][64];
    if (n >= N_NODES) return;
    int base = row[n];
    int deg  = row[n + 1] - base;
    int head = lane >> 4;
    float4 add = *(const float4*)(ad + n * 4);

    float4 l = make_float4(0.f, 0.f, 0.f, 0.f);
    float acc = 0.f;
    for (int c0 = 0; c0 < deg; c0 += 64) {
        int j = c0 + lane;
        int s = 0;
        float4 p = make_float4(0.f, 0.f, 0.f, 0.f);
        if (j < deg) {
            s = csr_src[base + j];
            float4 a = *(const float4*)(as + s * 4);
            p.x = __expf(lrelu(a.x + add.x));
            p.y = __expf(lrelu(a.y + add.y));
            p.z = __expf(lrelu(a.z + add.z));
            p.w = __expf(lrelu(a.w + add.w));
        }
        ls[wslot][lane] = s;
        lp4[wslot][lane] = p;
        float4 t = p;
        #pragma unroll
        for (int off = 32; off > 0; off >>= 1) {
            t.x += __shfl_xor(t.x, off);
            t.y += __shfl_xor(t.y, off);
            t.z += __shfl_xor(t.z, off);
            t.w += __shfl_xor(t.w, off);
        }
        l.x += t.x; l.y += t.y; l.z += t.z; l.w += t.w;
        int cnt = min(64, deg - c0);
        const int*   lsw = ls[wslot];
        const float* lpf = (const float*)lp4[wslot];
        int j2 = 0;
        for (; j2 + 8 <= cnt; j2 += 8) {
            float v[8];
            #pragma unroll
            for (int u = 0; u < 8; ++u) v[u] = h[lsw[j2+u] * 64 + lane];
            #pragma unroll
            for (int u = 0; u < 8; ++u) acc += lpf[(j2+u) * 4 + head] * v[u];
        }
        for (; j2 + 4 <= cnt; j2 += 4) {
            float v0 = h[lsw[j2+0] * 64 + lane];
            float v1 = h[lsw[j2+1] * 64 + lane];
            float v2 = h[lsw[j2+2] * 64 + lane];
            float v3 = h[lsw[j2+3] * 64 + lane];
            acc += lpf[(j2+0)*4+head]*v0 + lpf[(j2+1)*4+head]*v1
                 + lpf[(j2+2)*4+head]*v2 + lpf[(j2+3)*4+head]*v3;
        }
        for (; j2 < cnt; ++j2) {
            acc += lpf[j2 * 4 + head] * h[lsw[j2] * 64 + lane];
        }
    }
    float lh = (head == 0) ? l.x : (head == 1) ? l.y : (head == 2) ? l.z : l.w;
    out[(size_t)n * 64 + lane] = acc / (lh + 1e-16f);
}

// ---------------- decoder: 32 nodes/block, w1 in LDS ----------------
__global__ __launch_bounds__(256) void decoder32_kernel(
    const float* __restrict__ hin, const float* __restrict__ gb,
    const float* __restrict__ w1, const float* __restrict__ b1,
    const float* __restrict__ w2, const float* __restrict__ b2, float* __restrict__ out) {
    __shared__ float s_w1[4096];
    __shared__ float s_w2[256];
    __shared__ float s_h[32][64];
    __shared__ float s_t[32][64];
    int tid = threadIdx.x;
    int node0 = blockIdx.x * 32;
    for (int i = tid; i < 4096; i += 256) s_w1[i] = w1[i];
    if (tid < 256) s_w2[tid] = w2[tid];
    for (int i = tid; i < 2048; i += 256) {
        int nn = i >> 6, k = i & 63;
        int node = node0 + nn;
        s_h[nn][k] = (node < N_NODES ? hin[(size_t)node * 64 + k] : 0.f) + gb[k];
    }
    __syncthreads();
    int c = tid & 63;
    int mg = tid >> 6;
    float b1c = b1[c];
    float acc[8];
    #pragma unroll
    for (int m = 0; m < 8; ++m) acc[m] = b1c;
    #pragma unroll 4
    for (int k = 0; k < 64; ++k) {
        float w = s_w1[k * 64 + c];
        #pragma unroll
        for (int m = 0; m < 8; ++m) acc[m] += s_h[mg * 8 + m][k] * w;
    }
    #pragma unroll
    for (int m = 0; m < 8; ++m) s_t[mg * 8 + m][c] = fmaxf(acc[m], 0.f);
    __syncthreads();
    if (tid < 128) {
        int m = tid >> 2, j = tid & 3;
        int node = node0 + m;
        if (node < N_NODES) {
            float a = b2[j];
            #pragma unroll 16
            for (int k = 0; k < 64; ++k) a += s_t[m][k] * s_w2[k * 4 + j];
            out[node * 4 + j] = a;
        }
    }
}

extern "C" void kernel_launch(void* const* d_in, const int* in_sizes, int n_in,
                              void* d_out, int out_size, void* d_ws, size_t ws_size,
                              hipStream_t stream) {
    const float* x      = (const float*)d_in[0];
    const int*   ei     = (const int*)d_in[1];
    const float* enc_w1 = (const float*)d_in[2];
    const float* enc_b1 = (const float*)d_in[3];
    const float* enc_w2 = (const float*)d_in[4];
    const float* enc_b2 = (const float*)d_in[5];
    const float* g1_w   = (const float*)d_in[6];
    const float* g1_as  = (const float*)d_in[7];
    const float* g1_ad  = (const float*)d_in[8];
    const float* g1_b   = (const float*)d_in[9];
    const float* g2_w   = (const float*)d_in[10];
    const float* g2_as  = (const float*)d_in[11];
    const float* g2_ad  = (const float*)d_in[12];
    const float* g2_b   = (const float*)d_in[13];
    const float* dec_w1 = (const float*)d_in[14];
    const float* dec_b1 = (const float*)d_in[15];
    const float* dec_w2 = (const float*)d_in[16];
    const float* dec_b2 = (const float*)d_in[17];

    const int N = N_NODES, ET = ET_EDGES;

    // workspace layout (floats)
    float* ws   = (float*)d_ws;
    float* henc = ws;                        //  3,200,000
    float* agg  = ws + 3200000;              // 12,800,000
    float* h2   = ws + 16000000;             //  3,200,000
    float* out2 = ws + 19200000;             //  3,200,000
    float* as1  = ws + 22400000;             //    200,000
    float* ad1  = as1 + 200000;
    float* as2  = ad1 + 200000;
    float* ad2  = as2 + 200000;
    float* wsf  = ad2 + 200000;              // 256
    float* wdf  = wsf + 256;                 // 256
    int*   ib      = (int*)(ws + 23201024);
    int*   deg     = ib;                     // 50,001
    int*   rowp    = ib + 50004;             // 50,001
    int*   cursor  = ib + 100008;            // 50,001
    int*   bsum    = ib + 150012;            // 64
    int*   boff    = ib + 150076;            // 64
    int*   csr_src = ib + 150140;            // 850,000

    // zero deg + fold attention vectors (one dispatch)
    zerofold_kernel<<<64, 256, 0, stream>>>(deg, g1_w, g1_as, g1_ad, wsf, wdf);
    // edge count + encoder/alpha1 (one dispatch; independent halves overlap)
    count_enc_kernel<<<CNT_BLOCKS + ENC_BLOCKS, 256, 0, stream>>>(
        ei, deg, x, enc_w1, enc_b1, enc_w2, enc_b2, wsf, wdf, henc, as1, ad1);
    // CSR scan + scatter
    scanA_kernel<<<NBLK, 1024, 0, stream>>>(deg, rowp, bsum);
    scanB_kernel<<<1, 64, 0, stream>>>(bsum, boff, rowp);
    scanC_kernel<<<(N + 255) / 256, 256, 0, stream>>>(rowp, boff, cursor);
    scatter_kernel<<<(ET + 255) / 256, 256, 0, stream>>>(ei, cursor, csr_src);

    // GAT1: aggregate in henc-domain, then fused GEMM+ELU+GEMM+alpha2
    aggregate1_kernel<<<(N + 3) / 4, 256, 0, stream>>>(rowp, csr_src, as1, ad1, henc, agg);
    gat1_finish_kernel<<<N / 16, 256, 0, stream>>>(agg, g1_w, g1_b, g2_w, g2_as, g2_ad,
                                                   h2, as2, ad2);

    // GAT2
    aggregate2_kernel<<<(N + 3) / 4, 256, 0, stream>>>(rowp, csr_src, as2, ad2, h2, out2);

    decoder32_kernel<<<(N + 31) / 32, 256, 0, stream>>>(out2, g2_b, dec_w1, dec_b1, dec_w2, dec_b2, (float*)d_out);
}